// Round 3
// baseline (1383.967 us; speedup 1.0000x reference)
//
#include <hip/hip_runtime.h>
#include <math.h>

#define T_DIM 8192
#define H_DIM 4096
#define I_DIM 11008

typedef int v4i  __attribute__((ext_vector_type(4)));
typedef int v16i __attribute__((ext_vector_type(16)));

#define MFMA8 __builtin_amdgcn_mfma_i32_32x32x32_i8

// Plain compiler-tracked vector load: uniform SGPR base + per-lane 32-bit offset.
// The compiler emits global_load_dwordx4 (saddr form) and inserts counted
// s_waitcnt vmcnt(N) before first use — no async-writeback hazard.
__device__ __forceinline__ v4i LD(const char* base, unsigned off) {
  return *(const v4i*)(base + off);
}

// wave-uniform pointer (forces SGPR materialization)
__device__ __forceinline__ const char* rflp(const void* p) {
  unsigned lo = __builtin_amdgcn_readfirstlane((unsigned)(unsigned long long)p);
  unsigned hi = __builtin_amdgcn_readfirstlane((unsigned)((unsigned long long)p >> 32));
  return (const char*)(((unsigned long long)hi << 32) | lo);
}

// ---------------- pack + shuffle into MFMA-fragment order ----------------
// dst chunk c (16B): rk = c>>6, lane = c&63; r32 = rk/nk32, k32 = rk%nk32;
// row = r32*32 + (lane&31), k0 = k32*32 + (lane>>5)*16; bytes j = int8(src[row][k0+j]).
// A fragment load for MFMA step (r32,k32) is 64 lanes x 16B fully coalesced.
__global__ void pack_shuf(const int* __restrict__ src, char* __restrict__ dst,
                          int nk32, long nchunk) {
  long c = (long)blockIdx.x * blockDim.x + threadIdx.x;
  long stride = (long)gridDim.x * blockDim.x;
  for (; c < nchunk; c += stride) {
    int lane = (int)(c & 63);
    long rk = c >> 6;
    long r32 = rk / nk32;
    int k32 = (int)(rk - r32 * nk32);
    const int4* s = (const int4*)(src + (r32 * 32 + (lane & 31)) * (long)(nk32 * 32)
                                      + (long)k32 * 32 + ((lane >> 5) << 4));
    int4 a = s[0], b = s[1], cc = s[2], d = s[3];
    int w0 = (a.x & 255) | ((a.y & 255) << 8) | ((a.z & 255) << 16) | (a.w << 24);
    int w1 = (b.x & 255) | ((b.y & 255) << 8) | ((b.z & 255) << 16) | (b.w << 24);
    int w2 = (cc.x & 255) | ((cc.y & 255) << 8) | ((cc.z & 255) << 16) | (cc.w << 24);
    int w3 = (d.x & 255) | ((d.y & 255) << 8) | ((d.z & 255) << 16) | (d.w << 24);
    ((int4*)dst)[c] = make_int4(w0, w1, w2, w3);
  }
}

// ---------------- gate+up fused GEMM: LDS-FREE, register-only ----------------
// 256x128 tile, 8 waves (2M x 4N), wave = 128x32 x {gate,up}.
// Per K=32 step: 6 coalesced 1KB fragment loads (4 A + 2 B) + 8 MFMA.
// Triple-buffered, prefetch distance 2, compiler-managed waitcnt.
__global__ __launch_bounds__(512, 2) void gemm_gateup(
    const char* __restrict__ A, const char* __restrict__ Bg, const char* __restrict__ Bu,
    const float* __restrict__ ga_p, const float* __restrict__ gb,
    const float* __restrict__ ua_p, const float* __restrict__ ub,
    char* __restrict__ Q)
{
  const int tid = threadIdx.x;
  const int l = tid & 63;
  const int w = tid >> 6;
  const int wm = w >> 2, wn = w & 3;
  const int li32 = l & 31, kg2 = l >> 5;

  // XCD-chunked bijection (nwg=2752, %8==0) + 4x2 supertile.
  const int q8 = 2752 / 8;
  int bid = blockIdx.x;
  int wgid = (bid & 7) * q8 + (bid >> 3);
  int st = wgid >> 3, r = wgid & 7;
  int sm = st / 43, sn = st - sm * 43;
  const int m0 = (sm * 4 + (r & 3)) * 256;
  const int n0 = (sn * 2 + (r >> 2)) * 128;

  const int NK = H_DIM / 32;  // 128 K-steps

  v16i accg[4], accu[4];
#pragma unroll
  for (int i = 0; i < 4; ++i) {
#pragma unroll
    for (int j = 0; j < 16; ++j) { accg[i][j] = 0; accu[i][j] = 0; }
  }

  // Wave-uniform fragment bases (shuffled layout: [r32][k32][64][16]).
  const int r32b = (m0 >> 5) + wm * 4;
  const char* bA0 = rflp(A + ((size_t)(r32b + 0) * NK << 10));
  const char* bA1 = rflp(A + ((size_t)(r32b + 1) * NK << 10));
  const char* bA2 = rflp(A + ((size_t)(r32b + 2) * NK << 10));
  const char* bA3 = rflp(A + ((size_t)(r32b + 3) * NK << 10));
  const int n32 = (n0 >> 5) + wn;
  const char* bG = rflp(Bg + ((size_t)n32 * NK << 10));
  const char* bU = rflp(Bu + ((size_t)n32 * NK << 10));

  unsigned vp = (unsigned)(l * 16);
  const unsigned vmax = (unsigned)((NK - 1) * 1024 + l * 16);  // clamp OOB prefetch

  v4i X0, X1, X2, X3, Xg, Xu;
  v4i Y0, Y1, Y2, Y3, Yg, Yu;
  v4i Z0, Z1, Z2, Z3, Zg, Zu;

#define ISSUE_GU(S)                                                       \
  do {                                                                    \
    unsigned vo = vp < vmax ? vp : vmax;                                  \
    S##0 = LD(bA0, vo); S##1 = LD(bA1, vo);                               \
    S##2 = LD(bA2, vo); S##3 = LD(bA3, vo);                               \
    S##g = LD(bG, vo);  S##u = LD(bU, vo);                                \
    vp += 1024;                                                           \
  } while (0)

#define MM_GU(S)                                                          \
  do {                                                                    \
    __builtin_amdgcn_s_setprio(1);                                        \
    accg[0] = MFMA8(S##0, S##g, accg[0], 0, 0, 0);                        \
    accu[0] = MFMA8(S##0, S##u, accu[0], 0, 0, 0);                        \
    accg[1] = MFMA8(S##1, S##g, accg[1], 0, 0, 0);                        \
    accu[1] = MFMA8(S##1, S##u, accu[1], 0, 0, 0);                        \
    accg[2] = MFMA8(S##2, S##g, accg[2], 0, 0, 0);                        \
    accu[2] = MFMA8(S##2, S##u, accu[2], 0, 0, 0);                        \
    accg[3] = MFMA8(S##3, S##g, accg[3], 0, 0, 0);                        \
    accu[3] = MFMA8(S##3, S##u, accu[3], 0, 0, 0);                        \
    __builtin_amdgcn_s_setprio(0);                                        \
  } while (0)

  ISSUE_GU(X); ISSUE_GU(Y); ISSUE_GU(Z);   // 18 loads in flight

  for (int it = 0; it < 42; ++it) {        // steps 0..125
    MM_GU(X); ISSUE_GU(X);
    MM_GU(Y); ISSUE_GU(Y);
    MM_GU(Z); ISSUE_GU(Z);
  }
  MM_GU(X);                                // step 126
  MM_GU(Y);                                // step 127  (tail Z loads are dead/clamped)
#undef ISSUE_GU
#undef MM_GU

  // Epilogue: dequant -> SiLU(g)*u -> round-half-even -> clamp -> int8,
  // written in DOWN's shuffled-A layout: [r32][k32=col/32][lane][16B],
  // lane = (row&31) | (((col>>4)&1)<<5), byte = col&15.
  const float ga = *ga_p, ua = *ua_p;
  const int col = n0 + wn * 32 + li32;
  const float gbv = gb[col], ubv = ub[col];
  const int k32q = (n0 >> 5) + wn;
  const int lanehi = ((li32 >> 4) & 1) << 5;
  const int bytelo = li32 & 15;
  const int NKQ = I_DIM / 32;  // 344
#pragma unroll
  for (int mi = 0; mi < 4; ++mi) {
    const int r32q = (m0 >> 5) + wm * 4 + mi;
    char* qbase = Q + ((size_t)(r32q * NKQ + k32q) << 10);
#pragma unroll
    for (int rq = 0; rq < 4; ++rq) {
#pragma unroll
      for (int rr = 0; rr < 4; ++rr) {
        const int rg = rq * 4 + rr;
        const int rowin = kg2 * 4 + rq * 8 + rr;   // C/D row mapping (r1-verified)
        float g = (float)accg[mi][rg] * ga + gbv;
        float u = (float)accu[mi][rg] * ua + ubv;
        float x1 = g / (1.0f + expf(-g));
        float x = rintf(x1 * u);
        x = fminf(fmaxf(x, -128.0f), 127.0f);
        qbase[((rowin | lanehi) << 4) + bytelo] = (char)(int)x;
      }
    }
  }
}

// ---------------- down GEMM: LDS-FREE, register-only ----------------
// 256x256 tile, 8 waves (2M x 4N), wave = 128x64. Per K=32 step:
// 6 coalesced loads (4 A + 2 B) + 8 MFMA. Same pipeline as gateup.
__global__ __launch_bounds__(512, 2) void gemm_down(
    const char* __restrict__ Qm, const char* __restrict__ Bd,
    const float* __restrict__ da_p, const float* __restrict__ db,
    float* __restrict__ out)
{
  const int tid = threadIdx.x;
  const int l = tid & 63;
  const int w = tid >> 6;
  const int wm = w >> 2, wn = w & 3;
  const int li32 = l & 31, kg2 = l >> 5;

  const int q8 = 512 / 8;
  int bid = blockIdx.x;
  int wgid = (bid & 7) * q8 + (bid >> 3);
  int st = wgid >> 3, r = wgid & 7;
  int sm = st >> 3, sn = st & 7;
  const int m0 = (sm * 4 + (r & 3)) * 256;
  const int n0 = (sn * 2 + (r >> 2)) * 256;

  const int NK = I_DIM / 32;  // 344 K-steps

  v16i acc[4][2];
#pragma unroll
  for (int i = 0; i < 4; ++i) {
#pragma unroll
    for (int n = 0; n < 2; ++n) {
#pragma unroll
      for (int j = 0; j < 16; ++j) acc[i][n][j] = 0;
    }
  }

  const int r32b = (m0 >> 5) + wm * 4;
  const char* bA0 = rflp(Qm + ((size_t)(r32b + 0) * NK << 10));
  const char* bA1 = rflp(Qm + ((size_t)(r32b + 1) * NK << 10));
  const char* bA2 = rflp(Qm + ((size_t)(r32b + 2) * NK << 10));
  const char* bA3 = rflp(Qm + ((size_t)(r32b + 3) * NK << 10));
  const int n32b = (n0 >> 5) + wn * 2;
  const char* bB0 = rflp(Bd + ((size_t)(n32b + 0) * NK << 10));
  const char* bB1 = rflp(Bd + ((size_t)(n32b + 1) * NK << 10));

  unsigned vp = (unsigned)(l * 16);
  const unsigned vmax = (unsigned)((NK - 1) * 1024 + l * 16);

  v4i X0, X1, X2, X3, Xb0, Xb1;
  v4i Y0, Y1, Y2, Y3, Yb0, Yb1;
  v4i Z0, Z1, Z2, Z3, Zb0, Zb1;

#define ISSUE_DN(S)                                                       \
  do {                                                                    \
    unsigned vo = vp < vmax ? vp : vmax;                                  \
    S##0 = LD(bA0, vo);  S##1 = LD(bA1, vo);                              \
    S##2 = LD(bA2, vo);  S##3 = LD(bA3, vo);                              \
    S##b0 = LD(bB0, vo); S##b1 = LD(bB1, vo);                             \
    vp += 1024;                                                           \
  } while (0)

#define MM_DN(S)                                                          \
  do {                                                                    \
    __builtin_amdgcn_s_setprio(1);                                        \
    acc[0][0] = MFMA8(S##0, S##b0, acc[0][0], 0, 0, 0);                   \
    acc[0][1] = MFMA8(S##0, S##b1, acc[0][1], 0, 0, 0);                   \
    acc[1][0] = MFMA8(S##1, S##b0, acc[1][0], 0, 0, 0);                   \
    acc[1][1] = MFMA8(S##1, S##b1, acc[1][1], 0, 0, 0);                   \
    acc[2][0] = MFMA8(S##2, S##b0, acc[2][0], 0, 0, 0);                   \
    acc[2][1] = MFMA8(S##2, S##b1, acc[2][1], 0, 0, 0);                   \
    acc[3][0] = MFMA8(S##3, S##b0, acc[3][0], 0, 0, 0);                   \
    acc[3][1] = MFMA8(S##3, S##b1, acc[3][1], 0, 0, 0);                   \
    __builtin_amdgcn_s_setprio(0);                                        \
  } while (0)

  ISSUE_DN(X); ISSUE_DN(Y); ISSUE_DN(Z);   // 18 in flight

  for (int it = 0; it < 114; ++it) {       // steps 0..341
    MM_DN(X); ISSUE_DN(X);
    MM_DN(Y); ISSUE_DN(Y);
    MM_DN(Z); ISSUE_DN(Z);
  }
  MM_DN(X);                                // step 342
  MM_DN(Y);                                // step 343
#undef ISSUE_DN
#undef MM_DN

  const float da = *da_p;
#pragma unroll
  for (int ni = 0; ni < 2; ++ni) {
    const int col = n0 + wn * 64 + ni * 32 + li32;
    const float dbv = db[col];
#pragma unroll
    for (int mi = 0; mi < 4; ++mi) {
      const int rowb = m0 + wm * 128 + mi * 32 + kg2 * 4;
#pragma unroll
      for (int rq = 0; rq < 4; ++rq) {
#pragma unroll
        for (int rr = 0; rr < 4; ++rr)
          out[(size_t)(rowb + rq * 8 + rr) * H_DIM + col] =
              (float)acc[mi][ni][rq * 4 + rr] * da + dbv;
      }
    }
  }
}

extern "C" void kernel_launch(void* const* d_in, const int* in_sizes, int n_in,
                              void* d_out, int out_size, void* d_ws, size_t ws_size,
                              hipStream_t stream) {
  const int*   hs = (const int*)d_in[0];
  const int*   gw = (const int*)d_in[1];
  const float* ga = (const float*)d_in[2];
  const float* gb = (const float*)d_in[3];
  const int*   uw = (const int*)d_in[4];
  const float* ua = (const float*)d_in[5];
  const float* ub = (const float*)d_in[6];
  const int*   dw = (const int*)d_in[7];
  const float* da = (const float*)d_in[8];
  const float* db = (const float*)d_in[9];

  char* ws   = (char*)d_ws;
  char* hidS = ws;                                  // [256][128][64][16] shuffled
  char* gS   = hidS + (size_t)T_DIM * H_DIM;        // [344][128][64][16]
  char* uS   = gS   + (size_t)I_DIM * H_DIM;
  char* dS   = uS   + (size_t)I_DIM * H_DIM;        // [128][344][64][16]
  char* qS   = dS   + (size_t)H_DIM * I_DIM;        // [256][344][64][16]

  pack_shuf<<<2048, 256, 0, stream>>>(hs, hidS, H_DIM / 32, (long)T_DIM * H_DIM / 16);
  pack_shuf<<<2048, 256, 0, stream>>>(gw, gS,   H_DIM / 32, (long)I_DIM * H_DIM / 16);
  pack_shuf<<<2048, 256, 0, stream>>>(uw, uS,   H_DIM / 32, (long)I_DIM * H_DIM / 16);
  pack_shuf<<<2048, 256, 0, stream>>>(dw, dS,   I_DIM / 32, (long)H_DIM * I_DIM / 16);

  gemm_gateup<<<2752, 512, 0, stream>>>(hidS, gS, uS, ga, gb, ua, ub, qS);
  gemm_down<<<512, 512, 0, stream>>>(qS, dS, da, db, (float*)d_out);
}

// Round 4
// 1150.749 us; speedup vs baseline: 1.2027x; 1.2027x over previous
//
#include <hip/hip_runtime.h>
#include <math.h>

#define T_DIM 8192
#define H_DIM 4096
#define I_DIM 11008

typedef int v4i  __attribute__((ext_vector_type(4)));
typedef int v16i __attribute__((ext_vector_type(16)));

#define MFMA8 __builtin_amdgcn_mfma_i32_32x32x32_i8

#define AS1(p) ((const __attribute__((address_space(1))) void*)(p))
#define AS3(p) ((__attribute__((address_space(3))) void*)(p))

#define WAIT_VM_BAR(N) asm volatile("s_waitcnt vmcnt(" #N ")\n\ts_barrier" ::: "memory")
// counted LDS wait + scheduler fence (rule #18)
#define LGKM(N) do { asm volatile("s_waitcnt lgkmcnt(" #N ")" ::: "memory"); \
                     __builtin_amdgcn_sched_barrier(0); } while (0)

__device__ __forceinline__ v4i DSR(const char* p) {
  v4i r;
  unsigned a = (unsigned)(size_t)(const __attribute__((address_space(3))) char*)p;
  asm volatile("ds_read_b128 %0, %1" : "=v"(r) : "v"(a));
  return r;
}

#define STG(buf, src, soff, doff) \
  __builtin_amdgcn_global_load_lds(AS1((src) + (soff)), AS3((buf) + (doff) + dd), 16, 0, 0)

// ---------------- pack + shuffle into MFMA-fragment order (r3-verified) -------
// chunk c (16B): rk=c>>6, lane=c&63; r32=rk/nk32, k32=rk%nk32;
// row = r32*32+(lane&31), k0 = k32*32+(lane>>5)*16.
__global__ void pack_shuf(const int* __restrict__ src, char* __restrict__ dst,
                          int nk32, long nchunk) {
  long c = (long)blockIdx.x * blockDim.x + threadIdx.x;
  long stride = (long)gridDim.x * blockDim.x;
  for (; c < nchunk; c += stride) {
    int lane = (int)(c & 63);
    long rk = c >> 6;
    long r32 = rk / nk32;
    int k32 = (int)(rk - r32 * nk32);
    const int4* s = (const int4*)(src + (r32 * 32 + (lane & 31)) * (long)(nk32 * 32)
                                      + (long)k32 * 32 + ((lane >> 5) << 4));
    int4 a = s[0], b = s[1], cc = s[2], d = s[3];
    int w0 = (a.x & 255) | ((a.y & 255) << 8) | ((a.z & 255) << 16) | (a.w << 24);
    int w1 = (b.x & 255) | ((b.y & 255) << 8) | ((b.z & 255) << 16) | (b.w << 24);
    int w2 = (cc.x & 255) | ((cc.y & 255) << 8) | ((cc.z & 255) << 16) | (cc.w << 24);
    int w3 = (d.x & 255) | ((d.y & 255) << 8) | ((d.z & 255) << 16) | (d.w << 24);
    ((int4*)dst)[c] = make_int4(w0, w1, w2, w3);
  }
}

// ---------------- gate+up fused GEMM ----------------
// 256x128 tile, 8 waves (2M x 4N), BK=128 (4 k-steps), 2x64KB LDS dbuf.
// Per-tile buffer layout: step s in [0,4): A frags 8x1KB @ s*16K, G 4x1KB @ s*16K+8K,
// U 4x1KB @ s*16K+12K. Linear DMA dest, lane-linear ds_read -> 0 bank conflicts.
// Phase rhythm: read s+1 frags -> DMA -> lgkmcnt(6) -> 8 MFMA (step s).
__global__ __launch_bounds__(512, 2) void gemm_gateup(
    const char* __restrict__ A, const char* __restrict__ Bg, const char* __restrict__ Bu,
    const float* __restrict__ ga_p, const float* __restrict__ gb,
    const float* __restrict__ ua_p, const float* __restrict__ ub,
    char* __restrict__ Q)
{
  __shared__ char lds[2][65536];
  const int tid = threadIdx.x;
  const int l = tid & 63;
  const int w = tid >> 6;
  const int wm = w >> 2, wn = w & 3;
  const int li32 = l & 31, kg2 = l >> 5;

  // XCD-chunked bijection (nwg=2752, %8==0) + 4x2 supertile.
  const int q8 = 2752 / 8;
  int bid = blockIdx.x;
  int wgid = (bid & 7) * q8 + (bid >> 3);
  int st = wgid >> 3, r = wgid & 7;
  int sm = st / 43, sn = st - sm * 43;
  const int m0 = (sm * 4 + (r & 3)) * 256;
  const int n0 = (sn * 2 + (r >> 2)) * 128;

  const int NK = H_DIM / 32;   // 128 k32 steps total
  const int NT = H_DIM / 128;  // 32 K-tiles

  v16i accg[4], accu[4];
#pragma unroll
  for (int i = 0; i < 4; ++i) {
#pragma unroll
    for (int j = 0; j < 16; ++j) { accg[i][j] = 0; accu[i][j] = 0; }
  }

  // Per-thread DMA source pointers (shuffled layout [r32][k32][64][16]).
  const char* pA = A + ((size_t)((m0 >> 5) + (tid >> 6)) * NK << 10) + ((tid & 63) << 4);
  const char* pB = (tid < 256)
      ? Bg + ((size_t)((n0 >> 5) + (tid >> 6)) * NK << 10) + ((tid & 63) << 4)
      : Bu + ((size_t)((n0 >> 5) + ((tid >> 6) - 4)) * NK << 10) + ((tid & 63) << 4);
  const int dd = tid * 16;

  // Fragment read offsets (lane-linear within 1KB fragments).
  const int oA0 = (wm * 4 + 0) * 1024 + l * 16;
  const int oA1 = (wm * 4 + 1) * 1024 + l * 16;
  const int oA2 = (wm * 4 + 2) * 1024 + l * 16;
  const int oA3 = (wm * 4 + 3) * 1024 + l * 16;
  const int oG  = 8192  + wn * 1024 + l * 16;
  const int oU  = 12288 + wn * 1024 + l * 16;

  v4i E0, E1, E2, E3, Eg, Eu;
  v4i O0, O1, O2, O3, Og, Ou;

#define RD_GU(S, B, soff)                                                 \
  do {                                                                    \
    S##0 = DSR((B) + (soff) + oA0); S##1 = DSR((B) + (soff) + oA1);       \
    S##2 = DSR((B) + (soff) + oA2); S##3 = DSR((B) + (soff) + oA3);       \
    S##g = DSR((B) + (soff) + oG);  S##u = DSR((B) + (soff) + oU);        \
  } while (0)

#define MM_GU(S)                                                          \
  do {                                                                    \
    __builtin_amdgcn_s_setprio(1);                                        \
    accg[0] = MFMA8(S##0, S##g, accg[0], 0, 0, 0);                        \
    accu[0] = MFMA8(S##0, S##u, accu[0], 0, 0, 0);                        \
    accg[1] = MFMA8(S##1, S##g, accg[1], 0, 0, 0);                        \
    accu[1] = MFMA8(S##1, S##u, accu[1], 0, 0, 0);                        \
    accg[2] = MFMA8(S##2, S##g, accg[2], 0, 0, 0);                        \
    accu[2] = MFMA8(S##2, S##u, accu[2], 0, 0, 0);                        \
    accg[3] = MFMA8(S##3, S##g, accg[3], 0, 0, 0);                        \
    accu[3] = MFMA8(S##3, S##u, accu[3], 0, 0, 0);                        \
    __builtin_amdgcn_s_setprio(0);                                        \
  } while (0)

  {  // Prologue: stage tile 0 (8 chunks), certify, read step-0 fragments.
    char* B0 = lds[0];
    STG(B0, pA, 0,    0);     STG(B0, pA, 1024, 16384);
    STG(B0, pA, 2048, 32768); STG(B0, pA, 3072, 49152);
    STG(B0, pB, 0,    8192);  STG(B0, pB, 1024, 24576);
    STG(B0, pB, 2048, 40960); STG(B0, pB, 3072, 57344);
    WAIT_VM_BAR(0);
    RD_GU(E, B0, 0);
  }

  for (int t = 0; t < NT; ++t) {
    char* L  = lds[t & 1];
    char* SB = lds[(t & 1) ^ 1];
    const bool son = (t + 1) < NT;
    const long sk = (long)(t + 1) * 4096;

    // P0: read s1; DMA all A chunks of next tile; MFMA(s0)
    RD_GU(O, L, 16384);
    if (son) { STG(SB, pA, sk, 0);            STG(SB, pA, sk + 1024, 16384);
               STG(SB, pA, sk + 2048, 32768); STG(SB, pA, sk + 3072, 49152); }
    LGKM(6);
    MM_GU(E);
    // P1: read s2; DMA all B chunks; MFMA(s1)
    RD_GU(E, L, 32768);
    if (son) { STG(SB, pB, sk, 8192);         STG(SB, pB, sk + 1024, 24576);
               STG(SB, pB, sk + 2048, 40960); STG(SB, pB, sk + 3072, 57344); }
    LGKM(6);
    MM_GU(O);
    // P2: read s3; MFMA(s2)
    RD_GU(O, L, 49152);
    LGKM(6);
    MM_GU(E);
    // P3: MFMA(s3); tile boundary; read next tile's s0
    LGKM(0);
    MM_GU(O);
    __builtin_amdgcn_sched_barrier(0);
    WAIT_VM_BAR(0);   // per-wave 8 DMAs issued >=2 phases ago; certifies SB; L fully read
    if (son) RD_GU(E, SB, 0);
  }
#undef RD_GU
#undef MM_GU

  // Epilogue (r3-verified): dequant -> SiLU(g)*u -> rint -> clamp -> int8,
  // written in DOWN's shuffled layout: [r32][k32=col/32][lane][16B].
  const float ga = *ga_p, ua = *ua_p;
  const int col = n0 + wn * 32 + li32;
  const float gbv = gb[col], ubv = ub[col];
  const int k32q = (n0 >> 5) + wn;
  const int lanehi = ((li32 >> 4) & 1) << 5;
  const int bytelo = li32 & 15;
  const int NKQ = I_DIM / 32;  // 344
#pragma unroll
  for (int mi = 0; mi < 4; ++mi) {
    const int r32q = (m0 >> 5) + wm * 4 + mi;
    char* qbase = Q + ((size_t)(r32q * NKQ + k32q) << 10);
#pragma unroll
    for (int rq = 0; rq < 4; ++rq) {
#pragma unroll
      for (int rr = 0; rr < 4; ++rr) {
        const int rg = rq * 4 + rr;
        const int rowin = kg2 * 4 + rq * 8 + rr;
        float g = (float)accg[mi][rg] * ga + gbv;
        float u = (float)accu[mi][rg] * ua + ubv;
        float x1 = g / (1.0f + expf(-g));
        float x = rintf(x1 * u);
        x = fminf(fmaxf(x, -128.0f), 127.0f);
        qbase[((rowin | lanehi) << 4) + bytelo] = (char)(int)x;
      }
    }
  }
}

// ---------------- down GEMM ----------------
// 256x256 tile, 8 waves (2M x 4N), wave 128x64, BK=128, 2x64KB dbuf.
// Buffer per step s: A 8x1KB @ s*16K | B 8x1KB @ s*16K+8K. Same rhythm.
__global__ __launch_bounds__(512, 2) void gemm_down(
    const char* __restrict__ Qm, const char* __restrict__ Bd,
    const float* __restrict__ da_p, const float* __restrict__ db,
    float* __restrict__ out)
{
  __shared__ char lds[2][65536];
  const int tid = threadIdx.x;
  const int l = tid & 63;
  const int w = tid >> 6;
  const int wm = w >> 2, wn = w & 3;
  const int li32 = l & 31, kg2 = l >> 5;

  const int q8 = 512 / 8;
  int bid = blockIdx.x;
  int wgid = (bid & 7) * q8 + (bid >> 3);
  int st = wgid >> 3, r = wgid & 7;
  int sm = st >> 3, sn = st & 7;
  const int m0 = (sm * 4 + (r & 3)) * 256;
  const int n0 = (sn * 2 + (r >> 2)) * 256;

  const int NK = I_DIM / 32;   // 344
  const int NT = I_DIM / 128;  // 86

  v16i acc[4][2];
#pragma unroll
  for (int i = 0; i < 4; ++i) {
#pragma unroll
    for (int n = 0; n < 2; ++n) {
#pragma unroll
      for (int j = 0; j < 16; ++j) acc[i][n][j] = 0;
    }
  }

  const char* pA = Qm + ((size_t)((m0 >> 5) + (tid >> 6)) * NK << 10) + ((tid & 63) << 4);
  const char* pB = Bd + ((size_t)((n0 >> 5) + (tid >> 6)) * NK << 10) + ((tid & 63) << 4);
  const int dd = tid * 16;

  const int oA0 = (wm * 4 + 0) * 1024 + l * 16;
  const int oA1 = (wm * 4 + 1) * 1024 + l * 16;
  const int oA2 = (wm * 4 + 2) * 1024 + l * 16;
  const int oA3 = (wm * 4 + 3) * 1024 + l * 16;
  const int oB0 = 8192 + (wn * 2 + 0) * 1024 + l * 16;
  const int oB1 = 8192 + (wn * 2 + 1) * 1024 + l * 16;

  v4i E0, E1, E2, E3, Eb0, Eb1;
  v4i O0, O1, O2, O3, Ob0, Ob1;

#define RD_DN(S, B, soff)                                                 \
  do {                                                                    \
    S##0 = DSR((B) + (soff) + oA0);  S##1 = DSR((B) + (soff) + oA1);      \
    S##2 = DSR((B) + (soff) + oA2);  S##3 = DSR((B) + (soff) + oA3);      \
    S##b0 = DSR((B) + (soff) + oB0); S##b1 = DSR((B) + (soff) + oB1);     \
  } while (0)

#define MM_DN(S)                                                          \
  do {                                                                    \
    __builtin_amdgcn_s_setprio(1);                                        \
    acc[0][0] = MFMA8(S##0, S##b0, acc[0][0], 0, 0, 0);                   \
    acc[0][1] = MFMA8(S##0, S##b1, acc[0][1], 0, 0, 0);                   \
    acc[1][0] = MFMA8(S##1, S##b0, acc[1][0], 0, 0, 0);                   \
    acc[1][1] = MFMA8(S##1, S##b1, acc[1][1], 0, 0, 0);                   \
    acc[2][0] = MFMA8(S##2, S##b0, acc[2][0], 0, 0, 0);                   \
    acc[2][1] = MFMA8(S##2, S##b1, acc[2][1], 0, 0, 0);                   \
    acc[3][0] = MFMA8(S##3, S##b0, acc[3][0], 0, 0, 0);                   \
    acc[3][1] = MFMA8(S##3, S##b1, acc[3][1], 0, 0, 0);                   \
    __builtin_amdgcn_s_setprio(0);                                        \
  } while (0)

  {
    char* B0 = lds[0];
    STG(B0, pA, 0,    0);     STG(B0, pA, 1024, 16384);
    STG(B0, pA, 2048, 32768); STG(B0, pA, 3072, 49152);
    STG(B0, pB, 0,    8192);  STG(B0, pB, 1024, 24576);
    STG(B0, pB, 2048, 40960); STG(B0, pB, 3072, 57344);
    WAIT_VM_BAR(0);
    RD_DN(E, B0, 0);
  }

  for (int t = 0; t < NT; ++t) {
    char* L  = lds[t & 1];
    char* SB = lds[(t & 1) ^ 1];
    const bool son = (t + 1) < NT;
    const long sk = (long)(t + 1) * 4096;

    RD_DN(O, L, 16384);
    if (son) { STG(SB, pA, sk, 0);            STG(SB, pA, sk + 1024, 16384);
               STG(SB, pA, sk + 2048, 32768); STG(SB, pA, sk + 3072, 49152); }
    LGKM(6);
    MM_DN(E);

    RD_DN(E, L, 32768);
    if (son) { STG(SB, pB, sk, 8192);         STG(SB, pB, sk + 1024, 24576);
               STG(SB, pB, sk + 2048, 40960); STG(SB, pB, sk + 3072, 57344); }
    LGKM(6);
    MM_DN(O);

    RD_DN(O, L, 49152);
    LGKM(6);
    MM_DN(E);

    LGKM(0);
    MM_DN(O);
    __builtin_amdgcn_sched_barrier(0);
    WAIT_VM_BAR(0);
    if (son) RD_DN(E, SB, 0);
  }
#undef RD_DN
#undef MM_DN

  const float da = *da_p;
#pragma unroll
  for (int ni = 0; ni < 2; ++ni) {
    const int col = n0 + wn * 64 + ni * 32 + li32;
    const float dbv = db[col];
#pragma unroll
    for (int mi = 0; mi < 4; ++mi) {
      const int rowb = m0 + wm * 128 + mi * 32 + kg2 * 4;
#pragma unroll
      for (int rq = 0; rq < 4; ++rq) {
#pragma unroll
        for (int rr = 0; rr < 4; ++rr)
          out[(size_t)(rowb + rq * 8 + rr) * H_DIM + col] =
              (float)acc[mi][ni][rq * 4 + rr] * da + dbv;
      }
    }
  }
}

extern "C" void kernel_launch(void* const* d_in, const int* in_sizes, int n_in,
                              void* d_out, int out_size, void* d_ws, size_t ws_size,
                              hipStream_t stream) {
  const int*   hs = (const int*)d_in[0];
  const int*   gw = (const int*)d_in[1];
  const float* ga = (const float*)d_in[2];
  const float* gb = (const float*)d_in[3];
  const int*   uw = (const int*)d_in[4];
  const float* ua = (const float*)d_in[5];
  const float* ub = (const float*)d_in[6];
  const int*   dw = (const int*)d_in[7];
  const float* da = (const float*)d_in[8];
  const float* db = (const float*)d_in[9];

  char* ws   = (char*)d_ws;
  char* hidS = ws;                                  // [256][128][64][16] shuffled
  char* gS   = hidS + (size_t)T_DIM * H_DIM;        // [344][128][64][16]
  char* uS   = gS   + (size_t)I_DIM * H_DIM;
  char* dS   = uS   + (size_t)I_DIM * H_DIM;        // [128][344][64][16]
  char* qS   = dS   + (size_t)H_DIM * I_DIM;        // [256][344][64][16]

  pack_shuf<<<2048, 256, 0, stream>>>(hs, hidS, H_DIM / 32, (long)T_DIM * H_DIM / 16);
  pack_shuf<<<2048, 256, 0, stream>>>(gw, gS,   H_DIM / 32, (long)I_DIM * H_DIM / 16);
  pack_shuf<<<2048, 256, 0, stream>>>(uw, uS,   H_DIM / 32, (long)I_DIM * H_DIM / 16);
  pack_shuf<<<2048, 256, 0, stream>>>(dw, dS,   I_DIM / 32, (long)H_DIM * I_DIM / 16);

  gemm_gateup<<<2752, 512, 0, stream>>>(hidS, gS, uS, ga, gb, ua, ub, qS);
  gemm_down<<<512, 512, 0, stream>>>(qS, dS, da, db, (float*)d_out);
}